// Round 2
// baseline (487.853 us; speedup 1.0000x reference)
//
#include <hip/hip_runtime.h>

// CRF loss (B=1024, T=512, L=62, K=64) for MI355X / gfx950.
// Forward: one block (4 waves, 256 thr) per batch. Linear-domain recursion
//   q_j <- W_j * sum_i q_i E_ij, E = exp(trans) (rows 62/63 == 0 exactly),
//   i-dimension split 4 ways across waves, partials combined in LDS each step
//   (double-buffered, one barrier/step). Exact renorm every 4 steps via
//   c_total += log2(ssum_0), q *= rcp(ssum_0). First step analytic (uniform
//   SMALL pulled into c_total); final step done in log domain (e_s +1000
//   would overflow linear).
// Gold: 256 thr/batch gather. Reduce: single block.

#define SMALLF   (-1000.0f)
#define LOG2E_F  1.4426950408889634f
#define LN2_D    0.6931471805599453

#if defined(__has_builtin)
#if __has_builtin(__builtin_amdgcn_exp2f)
#define EXP2F(x) __builtin_amdgcn_exp2f(x)
#else
#define EXP2F(x) exp2f(x)
#endif
#if __has_builtin(__builtin_amdgcn_logf)
#define LOG2F(x) __builtin_amdgcn_logf(x)
#else
#define LOG2F(x) log2f(x)
#endif
#if __has_builtin(__builtin_amdgcn_rcpf)
#define RCPF(x) __builtin_amdgcn_rcpf(x)
#else
#define RCPF(x) (1.0f / (x))
#endif
#else
#define EXP2F(x) exp2f(x)
#define LOG2F(x) log2f(x)
#define RCPF(x) (1.0f / (x))
#endif

__device__ __forceinline__ float bcast_lane(float v, int lane) {
    return __uint_as_float(__builtin_amdgcn_readlane(__float_as_uint(v), lane));
}
__device__ __forceinline__ float bcast_first(float v) {
    return __uint_as_float(__builtin_amdgcn_readfirstlane(__float_as_uint(v)));
}

// ---------------- forward kernel: 4 waves per batch ----------------
__global__ __launch_bounds__(256) void crf_forward_kernel(
    const float* __restrict__ pred,     // (B,T,L)
    const int*   __restrict__ seq_len,  // (B,)
    const float* __restrict__ trans,    // (64,64)
    float*       __restrict__ fwd_out,  // (B,) base-2 scaled logZ
    int T, int L)
{
    const int b    = blockIdx.x;
    const int tid  = threadIdx.x;
    const int lane = tid & 63;
    const int w    = tid >> 6;          // wave id 0..3, owns E rows 16w..16w+15

    __shared__ __align__(16) float part[2][256];  // [buf][j*4 + w]
    __shared__ float alpha_sh[64];

    // E rows owned by this wave (full 64-wide vectors, lane = column j)
    float E[16];
#pragma unroll
    for (int k = 0; k < 16; ++k)
        E[k] = EXP2F(trans[(16 * w + k) * 64 + lane] * LOG2E_F);  // rows 62,63 -> 0

    const int slen  = seq_len[b];
    const int t_end = slen + 1;
    const int nmid  = t_end - 2;        // middle steps, 0..T-1
    const float* prow = pred + (size_t)b * T * L;

    const bool mine = ((lane >> 4) == w) && (lane < 62);  // obs-load / q-valid gate

    // prefetch ring: rows 1..8 (clamped), each wave loads only its 16-col slice
    float ring[8];
#pragma unroll
    for (int u = 0; u < 8; ++u) {
        int rr = (1 + u < T) ? (1 + u) : (T - 1);
        ring[u] = mine ? prow[(size_t)rr * L + lane] : 0.f;
    }

    // ---- init step (t=1): p_i = 1 for i<62 (rows 62/63 have E==0 anyway)
    float p0 = 0.f;
#pragma unroll
    for (int k = 0; k < 16; ++k) p0 += E[k];
    part[0][lane * 4 + w] = p0;
    __syncthreads();
    float4 pp = *(const float4*)&part[0][lane * 4];
    float ssum = (pp.x + pp.y) + (pp.z + pp.w);   // = sum_{i<62} E[i][j], all lanes
    float pv0 = mine ? prow[lane] : 0.f;          // pred row 0
    float q = ssum * (mine ? EXP2F(pv0 * LOG2E_F) : 0.f);
    float c_total = SMALLF * LOG2E_F;             // uniform SMALL from b_s init
    int buf = 1;

    // ---- middle steps t = 2 .. t_end-1 (obs = pred row t-1 = 1+m)
    for (int m = 0; m < nmid; ++m) {
        float pv = ring[m & 7];
        int rr = (9 + m < T) ? (9 + m) : (T - 1);
        ring[m & 7] = mine ? prow[(size_t)rr * L + lane] : 0.f;
        float Wm = EXP2F(pv * LOG2E_F);           // valid on 'mine' lanes only

        // partial matvec over this wave's 16 rows
        float a0 = 0.f, a1 = 0.f, a2 = 0.f, a3 = 0.f;
        const int base = w * 16;
#pragma unroll
        for (int k = 0; k < 16; k += 4) {
            a0 = fmaf(bcast_lane(q, base + k + 0), E[k + 0], a0);
            a1 = fmaf(bcast_lane(q, base + k + 1), E[k + 1], a1);
            a2 = fmaf(bcast_lane(q, base + k + 2), E[k + 2], a2);
            a3 = fmaf(bcast_lane(q, base + k + 3), E[k + 3], a3);
        }
        part[buf][lane * 4 + w] = (a0 + a1) + (a2 + a3);
        __syncthreads();
        float4 t4 = *(const float4*)&part[buf][lane * 4];
        ssum = (t4.x + t4.y) + (t4.z + t4.w);     // full sum, all lanes correct
        q = ssum * Wm;                            // garbage outside 'mine' (never read)
        if ((m & 3) == 3) {                       // exact renorm every 4 steps
            float s0 = bcast_first(ssum);
            c_total += LOG2F(s0);
            q *= RCPF(s0);
        }
        buf ^= 1;
    }

    // ---- final step t = t_end, in log domain (e_s has +1000)
    {
        float a0 = 0.f, a1 = 0.f, a2 = 0.f, a3 = 0.f;
        const int base = w * 16;
#pragma unroll
        for (int k = 0; k < 16; k += 4) {
            a0 = fmaf(bcast_lane(q, base + k + 0), E[k + 0], a0);
            a1 = fmaf(bcast_lane(q, base + k + 1), E[k + 1], a1);
            a2 = fmaf(bcast_lane(q, base + k + 2), E[k + 2], a2);
            a3 = fmaf(bcast_lane(q, base + k + 3), E[k + 3], a3);
        }
        part[buf][lane * 4 + w] = (a0 + a1) + (a2 + a3);
        __syncthreads();
        float4 t4 = *(const float4*)&part[buf][lane * 4];
        float ssf = (t4.x + t4.y) + (t4.z + t4.w);

        // obs at t_end: base (pred row t_end-1 if t_end<=T else r_pad) + e_s
        float pvf = (t_end <= T) ? ring[nmid & 7] : 0.f;  // ring[nmid&7] = row t_end-1
        float ob;
        if (lane < 62)       ob = pvf + SMALLF;   // pred (or 0) + e_s SMALL
        else if (lane == 62) ob = SMALLF;         // SMALL + 0
        else                 ob = 0.f;            // SMALL + 1000
        float alpha = c_total + LOG2F(ssf) + ob * LOG2E_F;

        bool wr = mine || (w == 3 && lane >= 62);
        if (wr) alpha_sh[lane] = alpha;
        __syncthreads();
        if (w == 0) {
            float a = alpha_sh[lane];
            float mx = a;
#pragma unroll
            for (int k = 32; k >= 1; k >>= 1)
                mx = fmaxf(mx, __shfl_xor(mx, k, 64));
            float pe = EXP2F(a - mx);
#pragma unroll
            for (int k = 32; k >= 1; k >>= 1)
                pe += __shfl_xor(pe, k, 64);
            if (lane == 0)
                fwd_out[b] = mx + LOG2F(pe);      // base-2; includes c_total via mx
        }
    }
}

// ---------------- gold-score kernel: 256 thr per batch ----------------
__global__ __launch_bounds__(256) void crf_gold_kernel(
    const float* __restrict__ pred,     // (B,T,L)
    const int*   __restrict__ ref,      // (B,T)
    const int*   __restrict__ seq_len,  // (B,)
    const float* __restrict__ trans,    // (64,64)
    float*       __restrict__ gold_out, // (B,)
    int T, int L)
{
    const int b    = blockIdx.x;
    const int tid  = threadIdx.x;
    const int lane = tid & 63;
    const int w    = tid >> 6;
    const int slen = seq_len[b];
    const int*   rrow = ref  + (size_t)b * T;
    const float* prow = pred + (size_t)b * T * L;

    __shared__ float gsm[4];

    float acc = 0.f;
    for (int t = tid; t < slen; t += 256) {
        const int c = rrow[t];
        acc += prow[(size_t)t * L + c];
        if (t >= 1) acc += trans[rrow[t - 1] * 64 + c];
    }
    if (tid == 0)
        acc += trans[62 * 64 + rrow[0]] + trans[rrow[slen - 1] * 64 + 63];
#pragma unroll
    for (int k = 32; k >= 1; k >>= 1)
        acc += __shfl_xor(acc, k, 64);
    if (lane == 0) gsm[w] = acc;
    __syncthreads();
    if (tid == 0) gold_out[b] = (gsm[0] + gsm[1]) + (gsm[2] + gsm[3]);
}

// ---------------- reduction kernel ----------------
__global__ __launch_bounds__(256) void crf_reduce_kernel(
    const float* __restrict__ fwd,   // (B,) base-2 scaled
    const float* __restrict__ gold,  // (B,)
    float*       __restrict__ out,
    int B)
{
    __shared__ double sm[256];
    const int tid = threadIdx.x;
    double s = 0.0;
    for (int i = tid; i < B; i += 256)
        s += (double)fwd[i] * LN2_D - (double)gold[i];
    sm[tid] = s;
    __syncthreads();
    for (int k = 128; k >= 1; k >>= 1) {
        if (tid < k) sm[tid] += sm[tid + k];
        __syncthreads();
    }
    if (tid == 0) out[0] = (float)sm[0];
}

extern "C" void kernel_launch(void* const* d_in, const int* in_sizes, int n_in,
                              void* d_out, int out_size, void* d_ws, size_t ws_size,
                              hipStream_t stream) {
    const float* pred  = (const float*)d_in[0];
    const int*   ref   = (const int*)  d_in[1];
    const int*   slen  = (const int*)  d_in[2];
    const float* trans = (const float*)d_in[3];

    const int B = in_sizes[2];                 // 1024
    const int T = in_sizes[1] / B;             // 512
    const int L = in_sizes[0] / (in_sizes[1]); // 62

    float* fwd  = (float*)d_ws;
    float* gold = fwd + B;

    crf_forward_kernel<<<B, 256, 0, stream>>>(pred, slen, trans, fwd, T, L);
    crf_gold_kernel  <<<B, 256, 0, stream>>>(pred, ref, slen, trans, gold, T, L);
    crf_reduce_kernel<<<1, 256, 0, stream>>>(fwd, gold, (float*)d_out, B);
}

// Round 3
// 397.675 us; speedup vs baseline: 1.2268x; 1.2268x over previous
//
#include <hip/hip_runtime.h>

// CRF loss (B=1024, T=512, L=62, K=64) for MI355X / gfx950.
// Single fused kernel: one 64-lane wave per batch (lane j = state j).
//   Forward recursion in LINEAR domain: q_j <- W_j * sum_i q_i E_ij,
//   E = exp(trans) precomputed in VGPRs (rows 62/63 are exactly 0).
//   Per step: 62 readlane broadcasts + 62 fma + 1 mul; W=exp2(obs) computed
//   off the serial chain from a prefetched ring. Exact renorm every 2 steps:
//   c_total += log2(ssum_lane0), q *= rcp(ssum_lane0).
//   First step analytic (uniform SMALL -> c_total); final step in log domain.
//   Gold path score gathered by the same wave; block atomicAdds
//   ln2*logZ2 - gold into out[0] (out zeroed via hipMemsetAsync).

#define SMALLF   (-1000.0f)
#define LOG2E_F  1.4426950408889634f
#define LN2_F    0.6931471805599453f

#if defined(__has_builtin)
#if __has_builtin(__builtin_amdgcn_exp2f)
#define EXP2F(x) __builtin_amdgcn_exp2f(x)
#else
#define EXP2F(x) exp2f(x)
#endif
#if __has_builtin(__builtin_amdgcn_logf)
#define LOG2F(x) __builtin_amdgcn_logf(x)
#else
#define LOG2F(x) log2f(x)
#endif
#if __has_builtin(__builtin_amdgcn_rcpf)
#define RCPF(x) __builtin_amdgcn_rcpf(x)
#else
#define RCPF(x) (1.0f / (x))
#endif
#else
#define EXP2F(x) exp2f(x)
#define LOG2F(x) log2f(x)
#define RCPF(x)  (1.0f / (x))
#endif

__device__ __forceinline__ float bcast_lane(float v, int lane) {
    return __uint_as_float(__builtin_amdgcn_readlane(__float_as_uint(v), lane));
}
__device__ __forceinline__ float bcast_first(float v) {
    return __uint_as_float(__builtin_amdgcn_readfirstlane(__float_as_uint(v)));
}

// 62-term matvec: ssum[lane] = sum_{i<62} q_i * E[i][lane].
// Phase-separated: all 62 broadcasts first (independent, pipeline back-to-back),
// then the FMA tree on 4 accumulators.
__device__ __forceinline__ float matvec62(const float q, const float* __restrict__ E) {
    float bc[62];
#pragma unroll
    for (int i = 0; i < 62; ++i) bc[i] = bcast_lane(q, i);
    float a0 = 0.f, a1 = 0.f, a2 = 0.f, a3 = 0.f;
#pragma unroll
    for (int i = 0; i < 60; i += 4) {
        a0 = fmaf(bc[i + 0], E[i + 0], a0);
        a1 = fmaf(bc[i + 1], E[i + 1], a1);
        a2 = fmaf(bc[i + 2], E[i + 2], a2);
        a3 = fmaf(bc[i + 3], E[i + 3], a3);
    }
    a0 = fmaf(bc[60], E[60], a0);
    a1 = fmaf(bc[61], E[61], a1);
    return (a0 + a1) + (a2 + a3);
}

__global__ __launch_bounds__(64, 1) void crf_fused_kernel(
    const float* __restrict__ pred,     // (B,T,L)
    const int*   __restrict__ ref,      // (B,T)
    const int*   __restrict__ seq_len,  // (B,)
    const float* __restrict__ trans,    // (64,64)
    float*       __restrict__ out,      // scalar, pre-zeroed
    int T, int L)
{
    const int b    = blockIdx.x;
    const int lane = threadIdx.x;
    const int slen = seq_len[b];
    const int nmid = slen - 1;          // middle steps t = 2 .. slen
    const float* prow = pred + (size_t)b * T * L;
    const int*   rrow = ref  + (size_t)b * T;
    const bool mine = (lane < 62);

    // ---- gold-score gather (independent of recursion; latency overlaps
    // across blocks and under the E-precompute below)
    float gacc = 0.f;
    for (int t = lane; t < slen; t += 64) {
        const int c = rrow[t];
        gacc += prow[(size_t)t * L + c];
        if (t >= 1) gacc += trans[rrow[t - 1] * 64 + c];
    }
    if (lane == 0)
        gacc += trans[62 * 64 + rrow[0]] + trans[rrow[slen - 1] * 64 + 63];

    // ---- E[i][lane] = exp(trans[i][lane]) for i<62 (rows 62/63 would be 0)
    float E[62];
#pragma unroll
    for (int i = 0; i < 62; ++i)
        E[i] = EXP2F(trans[i * 64 + lane] * LOG2E_F);

    // ---- prefetch ring: pred rows 1..8 (clamped)
    float ring[8];
#pragma unroll
    for (int u = 0; u < 8; ++u) {
        int rr = (1 + u < T) ? (1 + u) : (T - 1);
        ring[u] = mine ? prow[(size_t)rr * L + lane] : 0.f;
    }

    // ---- init (t=1): alpha1 = pred0 + SMALL + ln(sum_i e^trans[i][j])
    float p0 = 0.f;
#pragma unroll
    for (int i = 0; i < 62; ++i) p0 += E[i];
    float q = mine ? p0 * EXP2F(prow[lane] * LOG2E_F) : 0.f;
    float c_total = SMALLF * LOG2E_F;

    // ---- middle steps t = 2 .. slen  (obs = pred row t-1)
    for (int m = 0; m < nmid; ++m) {
        const float pv = ring[m & 7];
        const int rr = (9 + m < T) ? (9 + m) : (T - 1);
        const float nxt = mine ? prow[(size_t)rr * L + lane] : 0.f;
        const float W = EXP2F(pv * LOG2E_F);      // off the serial chain

        const float ssum = matvec62(q, E);
        q = ssum * W;
        ring[m & 7] = nxt;
        if (m & 1) {                               // exact renorm every 2 steps
            const float s0 = bcast_first(ssum);
            c_total += LOG2F(s0);
            q *= RCPF(s0);
        }
    }

    // ---- final step t = slen+1, log domain (e_s has +1000)
    {
        const float ssf = matvec62(q, E);          // >0 on all 64 lanes
        const float pvf = (slen + 1 <= T) ? ring[nmid & 7] : 0.f;
        float ob;
        if (lane < 62)       ob = pvf + SMALLF;    // pred/r_pad + e_s SMALL
        else if (lane == 62) ob = SMALLF;          // SMALL + 0
        else                 ob = 0.f;             // SMALL + 1000
        float alpha = c_total + LOG2F(ssf) + ob * LOG2E_F;

        // logsumexp over 64 states
        float mx = alpha;
#pragma unroll
        for (int k = 32; k >= 1; k >>= 1)
            mx = fmaxf(mx, __shfl_xor(mx, k, 64));
        float pe = EXP2F(alpha - mx);
#pragma unroll
        for (int k = 32; k >= 1; k >>= 1)
            pe += __shfl_xor(pe, k, 64);

        // gold reduce
#pragma unroll
        for (int k = 32; k >= 1; k >>= 1)
            gacc += __shfl_xor(gacc, k, 64);

        if (lane == 0) {
            const float logZ2 = mx + LOG2F(pe);    // base-2
            atomicAdd(out, LN2_F * logZ2 - gacc);
        }
    }
}

extern "C" void kernel_launch(void* const* d_in, const int* in_sizes, int n_in,
                              void* d_out, int out_size, void* d_ws, size_t ws_size,
                              hipStream_t stream) {
    const float* pred  = (const float*)d_in[0];
    const int*   ref   = (const int*)  d_in[1];
    const int*   slen  = (const int*)  d_in[2];
    const float* trans = (const float*)d_in[3];

    const int B = in_sizes[2];                 // 1024
    const int T = in_sizes[1] / B;             // 512
    const int L = in_sizes[0] / in_sizes[1];   // 62

    hipMemsetAsync(d_out, 0, sizeof(float), stream);
    crf_fused_kernel<<<B, 64, 0, stream>>>(pred, ref, slen, trans,
                                           (float*)d_out, T, L);
}

// Round 4
// 341.694 us; speedup vs baseline: 1.4278x; 1.1638x over previous
//
#include <hip/hip_runtime.h>

// CRF loss (B=1024, T=512, L=62, K=64) for MI355X / gfx950.
// One 64-lane wave per batch (lane j = state j). Linear-domain recursion
//   q_j <- W_j * sum_i q_i E_ij,  E = exp(trans) in VGPRs (rows 62/63 == 0).
// Matvec via LDS broadcast: qsh[lane]=q, then 16x ds_read_b128 (same-address
// broadcast, conflict-free) + 64 fma on 4 accumulators. No readlane hazards.
// Obs streaming: T-loop unrolled by 8 with named registers; next chunk's 8
// loads issued at chunk top -> 8 loads in flight, latency amortized.
// Exact renorm every 2 steps (c_total += log2(ssum_lane0), q *= rcp).
// First step analytic (uniform SMALL -> c_total); final step in log domain.
// Gold path score fused (two-phase gather); atomicAdd(ln2*logZ2 - gold).

#define SMALLF   (-1000.0f)
#define LOG2E_F  1.4426950408889634f
#define LN2_F    0.6931471805599453f

#if defined(__has_builtin)
#if __has_builtin(__builtin_amdgcn_exp2f)
#define EXP2F(x) __builtin_amdgcn_exp2f(x)
#else
#define EXP2F(x) exp2f(x)
#endif
#if __has_builtin(__builtin_amdgcn_logf)
#define LOG2F(x) __builtin_amdgcn_logf(x)
#else
#define LOG2F(x) log2f(x)
#endif
#if __has_builtin(__builtin_amdgcn_rcpf)
#define RCPF(x) __builtin_amdgcn_rcpf(x)
#else
#define RCPF(x) (1.0f / (x))
#endif
#else
#define EXP2F(x) exp2f(x)
#define LOG2F(x) log2f(x)
#define RCPF(x)  (1.0f / (x))
#endif

__device__ __forceinline__ float bcast_first(float v) {
    return __uint_as_float(__builtin_amdgcn_readfirstlane(__float_as_uint(v)));
}

// ssum[lane] = sum_{i<64} qsh[i] * E[i][lane]; E[62]=E[63]=0.
// All lanes read the same 16B -> LDS broadcast, conflict-free.
__device__ __forceinline__ float lds_matvec(const float* __restrict__ qsh,
                                            const float* __restrict__ E) {
    float a0 = 0.f, a1 = 0.f, a2 = 0.f, a3 = 0.f;
#pragma unroll
    for (int i = 0; i < 16; ++i) {
        const float4 v = reinterpret_cast<const float4*>(qsh)[i];
        a0 = fmaf(v.x, E[4 * i + 0], a0);
        a1 = fmaf(v.y, E[4 * i + 1], a1);
        a2 = fmaf(v.z, E[4 * i + 2], a2);
        a3 = fmaf(v.w, E[4 * i + 3], a3);
    }
    return (a0 + a1) + (a2 + a3);
}

__global__ __launch_bounds__(64, 1) void crf_fused_kernel(
    const float* __restrict__ pred,     // (B,T,L)
    const int*   __restrict__ ref,      // (B,T)
    const int*   __restrict__ seq_len,  // (B,)
    const float* __restrict__ trans,    // (64,64)
    float*       __restrict__ out,      // scalar, pre-zeroed
    int T, int L)
{
    const int b    = blockIdx.x;
    const int lane = threadIdx.x;
    const int slen = seq_len[b];
    const int nmid = slen - 1;              // middle steps t = 2..slen
    const float* prow = pred + (size_t)b * T * L;
    const int*   rrow = ref  + (size_t)b * T;
    const bool mine = (lane < 62);

    __shared__ __align__(16) float qsh[64];

    // ---- gold score, two-phase gather (indices first, then values)
    int cidx[8], pidx[8];
#pragma unroll
    for (int k = 0; k < 8; ++k) {
        const int t = lane + (k << 6);
        cidx[k] = (t < slen) ? rrow[t] : 0;
        pidx[k] = (t >= 1 && t < slen) ? rrow[t - 1] : 0;
    }
    float gacc = 0.f;
#pragma unroll
    for (int k = 0; k < 8; ++k) {
        const int t = lane + (k << 6);
        if (t < slen) {
            gacc += prow[(size_t)t * L + cidx[k]];
            if (t >= 1) gacc += trans[(pidx[k] << 6) + cidx[k]];
        }
    }
    if (lane == 0)
        gacc += trans[(62 << 6) + rrow[0]] + trans[(rrow[slen - 1] << 6) + 63];

    // ---- E[i] = exp(trans[i][lane]); rows 62/63 are -10000 -> exactly 0
    float E[64];
#pragma unroll
    for (int i = 0; i < 64; ++i)
        E[i] = EXP2F(trans[i * 64 + lane] * LOG2E_F);

    // ---- preload chunk 0 obs rows (rows 1..8, clamped)
    float cur[8];
#pragma unroll
    for (int u = 0; u < 8; ++u) {
        const int row = (u + 1 < T) ? (u + 1) : (T - 1);
        cur[u] = mine ? prow[(size_t)row * L + lane] : 0.f;
    }

    // ---- init (t=1): q = exp2(pred0) * sum_i E_i ; uniform SMALL -> c_total
    float p0 = 0.f;
#pragma unroll
    for (int i = 0; i < 64; ++i) p0 += E[i];
    float q = mine ? p0 * EXP2F(prow[lane] * LOG2E_F) : 0.f;
    float c_total = SMALLF * LOG2E_F;

    // ---- main loop: chunks of 8 middle steps; step m uses obs row m+1
    const int nfull = nmid >> 3;
    const int rem   = nmid & 7;
    for (int c = 0; c < nfull; ++c) {
        float W[8], nxt[8];
#pragma unroll
        for (int u = 0; u < 8; ++u)
            W[u] = EXP2F(cur[u] * LOG2E_F);     // off the serial chain
        const int base = 8 * (c + 1) + 1;
#pragma unroll
        for (int u = 0; u < 8; ++u) {           // issue next chunk's loads
            const int row = (base + u < T) ? (base + u) : (T - 1);
            nxt[u] = mine ? prow[(size_t)row * L + lane] : 0.f;
        }
#pragma unroll
        for (int u = 0; u < 8; ++u) {
            qsh[lane] = q;
            const float ssum = lds_matvec(qsh, E);
            q = ssum * W[u];
            if (u & 1) {                        // global m = 8c+u, parity = u&1
                const float s0 = bcast_first(ssum);
                c_total += LOG2F(s0);
                q *= RCPF(s0);
            }
        }
#pragma unroll
        for (int u = 0; u < 8; ++u) cur[u] = nxt[u];
    }

    // ---- remainder middle steps: cur[u] holds row 8*nfull+1+u
#pragma unroll
    for (int u = 0; u < 7; ++u) {
        if (u < rem) {
            const float W = EXP2F(cur[u] * LOG2E_F);
            qsh[lane] = q;
            const float ssum = lds_matvec(qsh, E);
            q = ssum * W;
            if (u & 1) {
                const float s0 = bcast_first(ssum);
                c_total += LOG2F(s0);
                q *= RCPF(s0);
            }
        }
    }

    // ---- final step t = slen+1 in log domain (e_s has +1000)
    {
        qsh[lane] = q;
        const float ssf = lds_matvec(qsh, E);    // > 0 on all 64 lanes
        const float pvf = (slen < T) ? cur[rem] : 0.f;  // row slen (or r_pad)
        float ob;
        if (lane < 62)       ob = pvf + SMALLF;  // pred/r_pad + e_s SMALL
        else if (lane == 62) ob = SMALLF;        // SMALL + 0
        else                 ob = 0.f;           // SMALL + 1000
        float alpha = c_total + LOG2F(ssf) + ob * LOG2E_F;

        float mx = alpha;
#pragma unroll
        for (int k = 32; k >= 1; k >>= 1)
            mx = fmaxf(mx, __shfl_xor(mx, k, 64));
        float pe = EXP2F(alpha - mx);
#pragma unroll
        for (int k = 32; k >= 1; k >>= 1)
            pe += __shfl_xor(pe, k, 64);
#pragma unroll
        for (int k = 32; k >= 1; k >>= 1)
            gacc += __shfl_xor(gacc, k, 64);

        if (lane == 0) {
            const float logZ2 = mx + LOG2F(pe);  // base-2
            atomicAdd(out, LN2_F * logZ2 - gacc);
        }
    }
}

extern "C" void kernel_launch(void* const* d_in, const int* in_sizes, int n_in,
                              void* d_out, int out_size, void* d_ws, size_t ws_size,
                              hipStream_t stream) {
    const float* pred  = (const float*)d_in[0];
    const int*   ref   = (const int*)  d_in[1];
    const int*   slen  = (const int*)  d_in[2];
    const float* trans = (const float*)d_in[3];

    const int B = in_sizes[2];                 // 1024
    const int T = in_sizes[1] / B;             // 512
    const int L = in_sizes[0] / in_sizes[1];   // 62

    hipMemsetAsync(d_out, 0, sizeof(float), stream);
    crf_fused_kernel<<<B, 64, 0, stream>>>(pred, ref, slen, trans,
                                           (float*)d_out, T, L);
}